// Round 1
// baseline (812.054 us; speedup 1.0000x reference)
//
#include <hip/hip_runtime.h>
#include <hip/hip_bf16.h>

#define T_ 4
#define B_ 8
#define N_ 512
#define C_ 512
#define H_ 8
#define D_ 64
#define BNR 4096      // B_*N_
#define BK 32
#define EPSf 1e-5f

// ---- fused: y = A @ W^T + bias -> BN(eval) -> LIF over T ----
// Each block: 64 rows (within B*N) x 64 cols, for ALL 4 timesteps.
// MODE 0: write head-split bf16 spikes (T,B,H,N,D). MODE 1: write fp32 spikes (T,B,N,C).
template<int MODE>
__global__ __launch_bounds__(256)
void gemm_bn_lif(const float* __restrict__ A, const float* __restrict__ W,
                 const float* __restrict__ bias, const float* __restrict__ gam,
                 const float* __restrict__ bet, const float* __restrict__ mea,
                 const float* __restrict__ rva, float vth,
                 __hip_bfloat16* __restrict__ out_hs, float* __restrict__ out_plain)
{
    __shared__ float As[T_][64][BK + 4];   // pad->stride 36: aligned b128 writes, 2-way (free) reads
    __shared__ float Bs[64][BK + 4];
    const int tid = threadIdx.x;
    const int tx = tid & 15, ty = tid >> 4;
    const int row0 = blockIdx.x * 64;      // row within B*N
    const int col0 = blockIdx.y * 64;      // output channel
    const int lr = tid >> 3;               // 0..31
    const int lk = (tid & 7) * 4;          // 0,4,...,28

    float acc[T_][4][4];
    #pragma unroll
    for (int t = 0; t < T_; ++t)
        #pragma unroll
        for (int i = 0; i < 4; ++i)
            #pragma unroll
            for (int j = 0; j < 4; ++j) acc[t][i][j] = 0.f;

    for (int k0 = 0; k0 < C_; k0 += BK) {
        __syncthreads();
        #pragma unroll
        for (int p = 0; p < 2; ++p) {
            const int o = lr + p * 32;
            *reinterpret_cast<float4*>(&Bs[o][lk]) =
                *reinterpret_cast<const float4*>(&W[(size_t)(col0 + o) * C_ + k0 + lk]);
        }
        #pragma unroll
        for (int t = 0; t < T_; ++t)
            #pragma unroll
            for (int p = 0; p < 2; ++p) {
                const int r = lr + p * 32;
                *reinterpret_cast<float4*>(&As[t][r][lk]) =
                    *reinterpret_cast<const float4*>(&A[((size_t)t * BNR + row0 + r) * C_ + k0 + lk]);
            }
        __syncthreads();
        #pragma unroll
        for (int kk = 0; kk < BK; ++kk) {
            float bfr[4];
            #pragma unroll
            for (int j = 0; j < 4; ++j) bfr[j] = Bs[tx * 4 + j][kk];
            #pragma unroll
            for (int t = 0; t < T_; ++t) {
                float afr[4];
                #pragma unroll
                for (int i = 0; i < 4; ++i) afr[i] = As[t][ty * 4 + i][kk];
                #pragma unroll
                for (int i = 0; i < 4; ++i)
                    #pragma unroll
                    for (int j = 0; j < 4; ++j)
                        acc[t][i][j] = fmaf(afr[i], bfr[j], acc[t][i][j]);
            }
        }
    }

    // BN params per output channel (mirror reference op order exactly)
    float sc[4], bi[4], mn[4], be[4];
    #pragma unroll
    for (int j = 0; j < 4; ++j) {
        const int c = col0 + tx * 4 + j;
        sc[j] = gam[c] * (1.0f / sqrtf(rva[c] + EPSf));
        bi[j] = bias[c]; mn[j] = mea[c]; be[j] = bet[c];
    }
    #pragma unroll
    for (int i = 0; i < 4; ++i) {
        const int rbn = row0 + ty * 4 + i;
        #pragma unroll
        for (int j = 0; j < 4; ++j) {
            const int c = col0 + tx * 4 + j;
            float v = 0.f;
            #pragma unroll
            for (int t = 0; t < T_; ++t) {
                const float y = ((acc[t][i][j] + bi[j]) - mn[j]) * sc[j] + be[j];
                v = v + (y - v) * 0.5f;                 // v += (x-v)/tau, tau=2
                const float s = (v >= vth) ? 1.0f : 0.0f;
                v = (s != 0.f) ? 0.f : v;               // hard reset
                if (MODE == 0) {
                    const int b = rbn >> 9, n = rbn & 511;
                    const int h = c >> 6, d = c & 63;
                    out_hs[((((size_t)t * B_ + b) * H_ + h) * N_ + n) * D_ + d] = __float2bfloat16(s);
                } else {
                    out_plain[((size_t)t * BNR + rbn) * C_ + c] = s;
                }
            }
        }
    }
}

// ---- kv[d1][d2] = sum_n k[n,d1] * v[n,d2]  per (t,b,h); exact integer counts ----
__global__ __launch_bounds__(256)
void ktv_kernel(const __hip_bfloat16* __restrict__ sk, const __hip_bfloat16* __restrict__ sv,
                float* __restrict__ kv)
{
    __shared__ __hip_bfloat16 kl[64][64];
    __shared__ __hip_bfloat16 vl[64][64];
    const int tbh = blockIdx.x;
    const int tid = threadIdx.x;
    const int tx = tid & 15, ty = tid >> 4;
    const size_t base = (size_t)tbh * N_ * D_;
    float acc[4][4] = {};
    for (int n0 = 0; n0 < N_; n0 += 64) {
        __syncthreads();
        #pragma unroll
        for (int p = 0; p < 2; ++p) {
            const int idx = tid + p * 256;
            const int r = idx >> 3, c8 = (idx & 7) * 8;
            *reinterpret_cast<float4*>(&kl[r][c8]) =
                *reinterpret_cast<const float4*>(&sk[base + (size_t)(n0 + r) * D_ + c8]);
            *reinterpret_cast<float4*>(&vl[r][c8]) =
                *reinterpret_cast<const float4*>(&sv[base + (size_t)(n0 + r) * D_ + c8]);
        }
        __syncthreads();
        for (int nn = 0; nn < 64; ++nn) {
            float a[4], b[4];
            #pragma unroll
            for (int i = 0; i < 4; ++i) a[i] = __bfloat162float(kl[nn][ty * 4 + i]);
            #pragma unroll
            for (int j = 0; j < 4; ++j) b[j] = __bfloat162float(vl[nn][tx * 4 + j]);
            #pragma unroll
            for (int i = 0; i < 4; ++i)
                #pragma unroll
                for (int j = 0; j < 4; ++j)
                    acc[i][j] = fmaf(a[i], b[j], acc[i][j]);
        }
    }
    float* out = kv + (size_t)tbh * 4096;
    #pragma unroll
    for (int i = 0; i < 4; ++i)
        #pragma unroll
        for (int j = 0; j < 4; ++j)
            out[(ty * 4 + i) * 64 + tx * 4 + j] = acc[i][j];
}

// ---- o = 0.125 * q @ kv, fused attn-LIF (vth=0.5) over t; writes (T,B,N,C) fp32 spikes ----
__global__ __launch_bounds__(256)
void qkv_lif_kernel(const __hip_bfloat16* __restrict__ sq, const float* __restrict__ kv,
                    float* __restrict__ osp)
{
    __shared__ float kvl[64][64];
    __shared__ __hip_bfloat16 ql[64][64];
    const int nt = blockIdx.x, b = blockIdx.y, h = blockIdx.z;
    const int tid = threadIdx.x;
    const int tx = tid & 15, ty = tid >> 4;
    const int n0 = nt * 64;
    float v[4][4] = {};
    for (int t = 0; t < T_; ++t) {
        const int tbh = (t * B_ + b) * H_ + h;
        __syncthreads();
        #pragma unroll
        for (int p = 0; p < 16; ++p) {
            const int idx = p * 256 + tid;
            kvl[idx >> 6][idx & 63] = kv[(size_t)tbh * 4096 + idx];
        }
        #pragma unroll
        for (int p = 0; p < 2; ++p) {
            const int idx = tid + p * 256;
            const int r = idx >> 3, c8 = (idx & 7) * 8;
            *reinterpret_cast<float4*>(&ql[r][c8]) =
                *reinterpret_cast<const float4*>(&sq[((size_t)tbh * N_ + n0 + r) * D_ + c8]);
        }
        __syncthreads();
        float acc[4][4] = {};
        for (int dd = 0; dd < 64; ++dd) {
            float a[4], bb[4];
            #pragma unroll
            for (int i = 0; i < 4; ++i) a[i] = __bfloat162float(ql[ty * 4 + i][dd]);
            #pragma unroll
            for (int j = 0; j < 4; ++j) bb[j] = kvl[dd][tx * 4 + j];
            #pragma unroll
            for (int i = 0; i < 4; ++i)
                #pragma unroll
                for (int j = 0; j < 4; ++j)
                    acc[i][j] = fmaf(a[i], bb[j], acc[i][j]);
        }
        #pragma unroll
        for (int i = 0; i < 4; ++i)
            #pragma unroll
            for (int j = 0; j < 4; ++j) {
                const float y = 0.125f * acc[i][j];     // exact
                float vv = v[i][j];
                vv = vv + (y - vv) * 0.5f;
                const float s = (vv >= 0.5f) ? 1.0f : 0.0f;
                osp[((size_t)(t * B_ + b) * N_ + n0 + ty * 4 + i) * C_ + h * 64 + tx * 4 + j] = s;
                v[i][j] = (s != 0.f) ? 0.f : vv;
            }
    }
}

extern "C" void kernel_launch(void* const* d_in, const int* in_sizes, int n_in,
                              void* d_out, int out_size, void* d_ws, size_t ws_size,
                              hipStream_t stream)
{
    const float* x = (const float*)d_in[0];
    const float *W[4], *bia[4], *gam[4], *bet[4], *mea[4], *rva[4];
    for (int br = 0; br < 4; ++br) {
        W[br]   = (const float*)d_in[1 + 6 * br + 0];
        bia[br] = (const float*)d_in[1 + 6 * br + 1];
        gam[br] = (const float*)d_in[1 + 6 * br + 2];
        bet[br] = (const float*)d_in[1 + 6 * br + 3];
        mea[br] = (const float*)d_in[1 + 6 * br + 4];
        rva[br] = (const float*)d_in[1 + 6 * br + 5];
    }
    char* ws = (char*)d_ws;
    __hip_bfloat16* sq = (__hip_bfloat16*)(ws + 0);
    __hip_bfloat16* sk = (__hip_bfloat16*)(ws + (size_t)16777216);
    __hip_bfloat16* sv = (__hip_bfloat16*)(ws + (size_t)33554432);
    float* kv  = (float*)(ws + (size_t)50331648);
    float* osp = (float*)(ws + (size_t)54525952);

    dim3 blk(256);
    dim3 ggrid(BNR / 64, C_ / 64);
    gemm_bn_lif<0><<<ggrid, blk, 0, stream>>>(x,   W[0], bia[0], gam[0], bet[0], mea[0], rva[0], 1.0f, sq, nullptr);
    gemm_bn_lif<0><<<ggrid, blk, 0, stream>>>(x,   W[1], bia[1], gam[1], bet[1], mea[1], rva[1], 1.0f, sk, nullptr);
    gemm_bn_lif<0><<<ggrid, blk, 0, stream>>>(x,   W[2], bia[2], gam[2], bet[2], mea[2], rva[2], 1.0f, sv, nullptr);
    ktv_kernel<<<dim3(T_ * B_ * H_), blk, 0, stream>>>(sk, sv, kv);
    qkv_lif_kernel<<<dim3(N_ / 64, B_, H_), blk, 0, stream>>>(sq, kv, osp);
    gemm_bn_lif<1><<<ggrid, blk, 0, stream>>>(osp, W[3], bia[3], gam[3], bet[3], mea[3], rva[3], 1.0f, nullptr, (float*)d_out);
}

// Round 2
// 196.433 us; speedup vs baseline: 4.1340x; 4.1340x over previous
//
#include <hip/hip_runtime.h>
#include <hip/hip_bf16.h>

typedef _Float16 h8 __attribute__((ext_vector_type(8)));
typedef _Float16 h4v __attribute__((ext_vector_type(4)));
typedef float f4 __attribute__((ext_vector_type(4)));

#define T_ 4
#define B_ 8
#define N_ 512
#define C_ 512
#define H_ 8
#define D_ 64
#define BNR 4096
#define EPSf 1e-5f
#define F16_MIN_NORM 6.1035156e-05f
#define INV4096 0.000244140625f

// ---- fp32 -> (h1 + 2^-12 * h2) f16 split, 4 elements/thread ----
__global__ __launch_bounds__(256)
void split_f16(const float* __restrict__ in, _Float16* __restrict__ h1,
               _Float16* __restrict__ h2, int n4)
{
    int i = blockIdx.x * 256 + threadIdx.x;
    if (i >= n4) return;
    float4 x = reinterpret_cast<const float4*>(in)[i];
    h4v a, b;
    #pragma unroll
    for (int j = 0; j < 4; ++j) {
        float xv = (&x.x)[j];
        float hi = (fabsf(xv) >= F16_MIN_NORM) ? xv : 0.0f;   // avoid f16 subnormal x1
        _Float16 h = (_Float16)hi;
        float r = (xv - (float)h) * 4096.0f;                  // normal-range residual
        a[j] = h; b[j] = (_Float16)r;
    }
    reinterpret_cast<h4v*>(h1)[i] = a;
    reinterpret_cast<h4v*>(h2)[i] = b;
}

// ---- MFMA GEMM (f16 split) + BN(eval) + LIF over T ----
// Block: 64 bn-rows x 64 cols x 4 timesteps. Wave w computes t=w; LIF via LDS tile.
// MODE 0: A = (A1,A2) split, 3 mfma/frag, out bf16 head-split (T,B,H,N,D).
// MODE 1: A = A1 exact f16 spikes, 2 mfma/frag, out fp32 (T,B,N,C).
template<int MODE>
__global__ __launch_bounds__(256, 2)
void mfma_gemm_bn_lif(const _Float16* __restrict__ A1, const _Float16* __restrict__ A2,
                      const _Float16* __restrict__ W1, const _Float16* __restrict__ W2,
                      const float* __restrict__ bias, const float* __restrict__ gam,
                      const float* __restrict__ bet, const float* __restrict__ mea,
                      const float* __restrict__ rva,
                      __hip_bfloat16* __restrict__ out_hs, float* __restrict__ out_plain)
{
    __shared__ __align__(16) char smem[65536];
    const int tid = threadIdx.x;
    // XCD swizzle: 8 col-tiles sharing an A-panel -> same XCD L2 chunk
    const int id = blockIdx.x;
    const int bt = (id & 7) * 8 + ((id >> 3) & 7);
    const int ct = id >> 6;
    const int row0 = bt * 64, col0 = ct * 64;
    const int wv = tid >> 6, lane = tid & 63;
    const int lr = lane & 15, lk = lane >> 4;
    const int WOFF = (MODE == 0) ? 32768 : 16384;

    f4 accA[4][4], accB[4][4];
    #pragma unroll
    for (int mi = 0; mi < 4; ++mi)
        #pragma unroll
        for (int ni = 0; ni < 4; ++ni) {
            accA[mi][ni] = (f4)0.0f;
            accB[mi][ni] = (f4)0.0f;
        }

    for (int k0 = 0; k0 < C_; k0 += 32) {
        __syncthreads();
        if (MODE == 0) {
            #pragma unroll
            for (int p = 0; p < 8; ++p) {               // A: 2 splits x 4t x 64m x 4g
                int idx = p * 256 + tid;
                int s = idx >> 10, rem = idx & 1023;
                int t = rem >> 8, r2 = rem & 255;
                int m = r2 >> 2, g = r2 & 3;
                const _Float16* src = s ? A2 : A1;
                h8 v = *reinterpret_cast<const h8*>(src + (size_t)(t * BNR + row0 + m) * C_ + k0 + g * 8);
                *reinterpret_cast<h8*>(smem + s * 16384 + t * 4096 + m * 64 + g * 16) = v;
            }
        } else {
            #pragma unroll
            for (int p = 0; p < 4; ++p) {               // A: 4t x 64m x 4g
                int idx = p * 256 + tid;
                int t = idx >> 8, r2 = idx & 255;
                int m = r2 >> 2, g = r2 & 3;
                h8 v = *reinterpret_cast<const h8*>(A1 + (size_t)(t * BNR + row0 + m) * C_ + k0 + g * 8);
                *reinterpret_cast<h8*>(smem + t * 4096 + m * 64 + g * 16) = v;
            }
        }
        #pragma unroll
        for (int p = 0; p < 2; ++p) {                   // W: 2 splits x 64n x 4g
            int idx = p * 256 + tid;
            int s = idx >> 8, r2 = idx & 255;
            int n = r2 >> 2, g = r2 & 3;
            const _Float16* src = s ? W2 : W1;
            h8 v = *reinterpret_cast<const h8*>(src + (size_t)(col0 + n) * C_ + k0 + g * 8);
            *reinterpret_cast<h8*>(smem + WOFF + s * 4096 + n * 64 + g * 16) = v;
        }
        __syncthreads();

        h8 a1[4], a2[4];
        #pragma unroll
        for (int mi = 0; mi < 4; ++mi) {
            int abase = wv * 4096 + (mi * 16 + lr) * 64 + lk * 16;
            a1[mi] = *reinterpret_cast<const h8*>(smem + abase);
            if (MODE == 0) a2[mi] = *reinterpret_cast<const h8*>(smem + 16384 + abase);
        }
        #pragma unroll
        for (int ni = 0; ni < 4; ++ni) {
            int bbase = WOFF + (ni * 16 + lr) * 64 + lk * 16;
            h8 b1 = *reinterpret_cast<const h8*>(smem + bbase);
            h8 b2 = *reinterpret_cast<const h8*>(smem + 4096 + bbase);
            #pragma unroll
            for (int mi = 0; mi < 4; ++mi) {
                accA[mi][ni] = __builtin_amdgcn_mfma_f32_16x16x32_f16(a1[mi], b1, accA[mi][ni], 0, 0, 0);
                accB[mi][ni] = __builtin_amdgcn_mfma_f32_16x16x32_f16(a1[mi], b2, accB[mi][ni], 0, 0, 0);
                if (MODE == 0)
                    accB[mi][ni] = __builtin_amdgcn_mfma_f32_16x16x32_f16(a2[mi], b1, accB[mi][ni], 0, 0, 0);
            }
        }
    }

    __syncthreads();
    // result tile -> LDS fp32 [4t][64][64], col XOR-swizzled to keep writes 2-way
    float* et = (float*)smem;
    #pragma unroll
    for (int mi = 0; mi < 4; ++mi)
        #pragma unroll
        for (int ni = 0; ni < 4; ++ni)
            #pragma unroll
            for (int r = 0; r < 4; ++r) {
                int row = mi * 16 + lk * 4 + r;          // C/D: row=(l>>4)*4+r, col=l&15
                int col = ni * 16 + lr;
                et[wv * 4096 + row * 64 + (col ^ ((row & 7) << 2))] =
                    accA[mi][ni][r] + INV4096 * accB[mi][ni][r];
            }
    __syncthreads();

    const int d = tid & 63;
    const int c = col0 + d;
    const float sc = gam[c] * (1.0f / sqrtf(rva[c] + EPSf));
    const float bi = bias[c], mn = mea[c], be = bet[c];
    const int rq = tid >> 6;
    #pragma unroll
    for (int q = 0; q < 16; ++q) {
        int r = rq * 16 + q;
        int bn = row0 + r;
        float vm = 0.0f;
        #pragma unroll
        for (int t = 0; t < T_; ++t) {
            float y = ((et[t * 4096 + r * 64 + (d ^ ((r & 7) << 2))] + bi) - mn) * sc + be;
            vm = vm + (y - vm) * 0.5f;
            float s = (vm >= 1.0f) ? 1.0f : 0.0f;
            vm = (s != 0.0f) ? 0.0f : vm;
            if (MODE == 0) {
                int b = bn >> 9, n = bn & 511;
                out_hs[((((size_t)t * B_ + b) * H_ + ct) * N_ + n) * D_ + d] = __float2bfloat16(s);
            } else {
                out_plain[(size_t)(t * BNR + bn) * C_ + c] = s;
            }
        }
    }
}

// ---- kv[d1][d2] = sum_n k[n,d1]*v[n,d2] per (t,b,h) ----
__global__ __launch_bounds__(256)
void ktv_kernel(const __hip_bfloat16* __restrict__ sk, const __hip_bfloat16* __restrict__ sv,
                float* __restrict__ kv)
{
    __shared__ __hip_bfloat16 kl[64][64];
    __shared__ __hip_bfloat16 vl[64][64];
    const int tbh = blockIdx.x;
    const int tid = threadIdx.x;
    const int tx = tid & 15, ty = tid >> 4;
    const size_t base = (size_t)tbh * N_ * D_;
    float acc[4][4] = {};
    for (int n0 = 0; n0 < N_; n0 += 64) {
        __syncthreads();
        #pragma unroll
        for (int p = 0; p < 2; ++p) {
            const int idx = tid + p * 256;
            const int r = idx >> 3, c8 = (idx & 7) * 8;
            *reinterpret_cast<float4*>(&kl[r][c8]) =
                *reinterpret_cast<const float4*>(&sk[base + (size_t)(n0 + r) * D_ + c8]);
            *reinterpret_cast<float4*>(&vl[r][c8]) =
                *reinterpret_cast<const float4*>(&sv[base + (size_t)(n0 + r) * D_ + c8]);
        }
        __syncthreads();
        for (int nn = 0; nn < 64; ++nn) {
            float a[4], b[4];
            #pragma unroll
            for (int i = 0; i < 4; ++i) a[i] = __bfloat162float(kl[nn][ty * 4 + i]);
            #pragma unroll
            for (int j = 0; j < 4; ++j) b[j] = __bfloat162float(vl[nn][tx * 4 + j]);
            #pragma unroll
            for (int i = 0; i < 4; ++i)
                #pragma unroll
                for (int j = 0; j < 4; ++j)
                    acc[i][j] = fmaf(a[i], b[j], acc[i][j]);
        }
    }
    float* out = kv + (size_t)tbh * 4096;
    #pragma unroll
    for (int i = 0; i < 4; ++i)
        #pragma unroll
        for (int j = 0; j < 4; ++j)
            out[(ty * 4 + i) * 64 + tx * 4 + j] = acc[i][j];
}

// ---- o = 0.125 * q @ kv, fused attn-LIF (vth=0.5); writes f16 spikes (T,B,N,C) ----
__global__ __launch_bounds__(256)
void qkv_lif_kernel(const __hip_bfloat16* __restrict__ sq, const float* __restrict__ kv,
                    _Float16* __restrict__ osp)
{
    __shared__ float kvl[64][64];
    __shared__ __hip_bfloat16 ql[64][64];
    const int nt = blockIdx.x, b = blockIdx.y, h = blockIdx.z;
    const int tid = threadIdx.x;
    const int tx = tid & 15, ty = tid >> 4;
    const int n0 = nt * 64;
    float v[4][4] = {};
    for (int t = 0; t < T_; ++t) {
        const int tbh = (t * B_ + b) * H_ + h;
        __syncthreads();
        #pragma unroll
        for (int p = 0; p < 16; ++p) {
            const int idx = p * 256 + tid;
            kvl[idx >> 6][idx & 63] = kv[(size_t)tbh * 4096 + idx];
        }
        #pragma unroll
        for (int p = 0; p < 2; ++p) {
            const int idx = tid + p * 256;
            const int r = idx >> 3, c8 = (idx & 7) * 8;
            *reinterpret_cast<float4*>(&ql[r][c8]) =
                *reinterpret_cast<const float4*>(&sq[((size_t)tbh * N_ + n0 + r) * D_ + c8]);
        }
        __syncthreads();
        float acc[4][4] = {};
        for (int dd = 0; dd < 64; ++dd) {
            float a[4], bb[4];
            #pragma unroll
            for (int i = 0; i < 4; ++i) a[i] = __bfloat162float(ql[ty * 4 + i][dd]);
            #pragma unroll
            for (int j = 0; j < 4; ++j) bb[j] = kvl[dd][tx * 4 + j];
            #pragma unroll
            for (int i = 0; i < 4; ++i)
                #pragma unroll
                for (int j = 0; j < 4; ++j)
                    acc[i][j] = fmaf(a[i], bb[j], acc[i][j]);
        }
        #pragma unroll
        for (int i = 0; i < 4; ++i)
            #pragma unroll
            for (int j = 0; j < 4; ++j) {
                const float y = 0.125f * acc[i][j];     // exact (integer counts)
                float vv = v[i][j];
                vv = vv + (y - vv) * 0.5f;
                const float s = (vv >= 0.5f) ? 1.0f : 0.0f;
                osp[((size_t)(t * B_ + b) * N_ + n0 + ty * 4 + i) * C_ + h * 64 + tx * 4 + j] = (_Float16)s;
                v[i][j] = (s != 0.0f) ? 0.0f : vv;
            }
    }
}

extern "C" void kernel_launch(void* const* d_in, const int* in_sizes, int n_in,
                              void* d_out, int out_size, void* d_ws, size_t ws_size,
                              hipStream_t stream)
{
    const float* x = (const float*)d_in[0];
    const float *W[4], *bia[4], *gam[4], *bet[4], *mea[4], *rva[4];
    for (int br = 0; br < 4; ++br) {
        W[br]   = (const float*)d_in[1 + 6 * br + 0];
        bia[br] = (const float*)d_in[1 + 6 * br + 1];
        gam[br] = (const float*)d_in[1 + 6 * br + 2];
        bet[br] = (const float*)d_in[1 + 6 * br + 3];
        mea[br] = (const float*)d_in[1 + 6 * br + 4];
        rva[br] = (const float*)d_in[1 + 6 * br + 5];
    }
    char* ws = (char*)d_ws;
    _Float16* x1 = (_Float16*)(ws + 0);
    _Float16* x2 = (_Float16*)(ws + 16777216);
    __hip_bfloat16* sq = (__hip_bfloat16*)(ws + 33554432);
    __hip_bfloat16* sk = (__hip_bfloat16*)(ws + 50331648);
    __hip_bfloat16* sv = (__hip_bfloat16*)(ws + 67108864);
    _Float16* w1[4], *w2[4];
    for (int br = 0; br < 4; ++br) {
        w1[br] = (_Float16*)(ws + 83886080 + (size_t)br * 1048576);
        w2[br] = (_Float16*)(ws + 83886080 + (size_t)br * 1048576 + 524288);
    }
    float*    kv  = (float*)(ws + 16777216);     // aliases x2 (dead after 3rd GEMM)
    _Float16* osp = (_Float16*)(ws + 0);         // aliases x1 (dead after 3rd GEMM)

    dim3 blk(256);
    split_f16<<<dim3(8192), blk, 0, stream>>>(x, x1, x2, 2097152);
    for (int br = 0; br < 4; ++br)
        split_f16<<<dim3(256), blk, 0, stream>>>(W[br], w1[br], w2[br], 65536);

    mfma_gemm_bn_lif<0><<<dim3(512), blk, 0, stream>>>(x1, x2, w1[0], w2[0],
        bia[0], gam[0], bet[0], mea[0], rva[0], sq, nullptr);
    mfma_gemm_bn_lif<0><<<dim3(512), blk, 0, stream>>>(x1, x2, w1[1], w2[1],
        bia[1], gam[1], bet[1], mea[1], rva[1], sk, nullptr);
    mfma_gemm_bn_lif<0><<<dim3(512), blk, 0, stream>>>(x1, x2, w1[2], w2[2],
        bia[2], gam[2], bet[2], mea[2], rva[2], sv, nullptr);

    ktv_kernel<<<dim3(T_ * B_ * H_), blk, 0, stream>>>(sk, sv, kv);
    qkv_lif_kernel<<<dim3(N_ / 64, B_, H_), blk, 0, stream>>>(sq, kv, osp);

    mfma_gemm_bn_lif<1><<<dim3(512), blk, 0, stream>>>(osp, nullptr, w1[3], w2[3],
        bia[3], gam[3], bet[3], mea[3], rva[3], nullptr, (float*)d_out);
}